// Round 5
// baseline (3638.913 us; speedup 1.0000x reference)
//
#include <hip/hip_runtime.h>
#include <hip/hip_bf16.h>

// ---------------------------------------------------------------------------
// InvSlotAttentionGuide: CNN encoder -> pos embed -> MLP -> slot attention
// with MESH-Sinkhorn (manual reverse-mode through 5 sinkhorn iters).
// Inputs f32 (runtime sniff guards dtype); pipeline f32; OUTPUT f32
// (reference output dtype is float32 — writing bf16 here was the round-2..4
// stable-8.23 failure). Peak workspace 39.4 MiB.
// ---------------------------------------------------------------------------

#define LN_EPS 1e-5f
#define SEPS 1e-8f
#define LN8 2.0794415416798357f

__device__ inline float wmaxall(float v) {
#pragma unroll
  for (int o = 32; o; o >>= 1) v = fmaxf(v, __shfl_down(v, o));
  return __shfl(v, 0);
}
__device__ inline float wsumall(float v) {
#pragma unroll
  for (int o = 32; o; o >>= 1) v += __shfl_down(v, o);
  return __shfl(v, 0);
}
__device__ inline int wsumi(int v) {
#pragma unroll
  for (int o = 32; o; o >>= 1) v += __shfl_down(v, o);
  return __shfl(v, 0);
}

// ---------------------------------------------------------------------------
// dtype sniff: low half-words of f32 data are mantissa bits (uniform);
// low half-words of packed bf16 N(0,1) data have exponent in ~[117,129].
// ---------------------------------------------------------------------------
__global__ __launch_bounds__(64) void sniff_kernel(const unsigned int* __restrict__ img,
                                                   int* __restrict__ flag) {
  int cnt = 0;
  for (int i = threadIdx.x; i < 512; i += 64) {
    unsigned lo = img[i] & 0xFFFFu;
    int e = (int)((lo >> 7) & 0xFFu);
    cnt += (e >= 96 && e <= 140) ? 1 : 0;
  }
  cnt = wsumi(cnt);
  if (threadIdx.x == 0) *flag = (cnt >= 300) ? 1 : 0;
}

struct CvtArgs {
  const void* src[39];
  long off[40];
};

__global__ __launch_bounds__(256) void convert_kernel(CvtArgs a, const int* __restrict__ flag,
                                                      float* __restrict__ dst, long total) {
  const int isbf = *flag;
  for (long g = (long)blockIdx.x * 256 + threadIdx.x; g < total; g += (long)gridDim.x * 256) {
    int lo = 0, hi = 38;
    while (lo < hi) {
      int mid = (lo + hi + 1) >> 1;
      if (a.off[mid] <= g) lo = mid; else hi = mid - 1;
    }
    long li = g - a.off[lo];
    float v;
    if (isbf) {
      v = __bfloat162float(((const __hip_bfloat16*)a.src[lo])[li]);
    } else {
      v = ((const float*)a.src[lo])[li];
    }
    dst[g] = v;
  }
}

// ---------------------------------------------------------------------------
// Direct 5x5 conv + bias + relu, pad=2, with row-window slicing. f32 in/out.
// 16x16 output tile, 16 oc per block. grid: (tileRows*tilesX, Cout/16, B).
// oybeg/oyend = output-row window; ibase/irows = input buffer window;
// obase/orows = output buffer window (absolute row coords).
// ---------------------------------------------------------------------------
template <int S>
__global__ __launch_bounds__(256) void conv5x5(
    const float* __restrict__ in, const float* __restrict__ wgt,
    const float* __restrict__ bias, float* __restrict__ out,
    int Cin, int H, int W, int Wo, int Cout, int tilesX,
    int oybeg, int oyend, int ibase, int irows, int obase, int orows) {
  constexpr int P = 15 * S + 5;  // patch dim: 20 (S=1) or 35 (S=2)
  __shared__ float patch[P * P];
  __shared__ float wt[16 * 25];
  const int b = blockIdx.z;
  const int ocg = blockIdx.y * 16;
  const int ty0 = oybeg + (blockIdx.x / tilesX) * 16, tx0 = (blockIdx.x % tilesX) * 16;
  const int tx = threadIdx.x & 15, ty = threadIdx.x >> 4;
  const int iy0 = ty0 * S - 2, ix0 = tx0 * S - 2;
  float acc[16];
#pragma unroll
  for (int j = 0; j < 16; j++) acc[j] = 0.f;

  for (int ci = 0; ci < Cin; ++ci) {
    const float* inp = in + ((long)b * Cin + ci) * (long)irows * W;
    for (int idx = threadIdx.x; idx < P * P; idx += 256) {
      int py = idx / P, px = idx - py * P;
      int iy = iy0 + py, ix = ix0 + px;
      float v = 0.f;
      if (iy >= 0 && iy < H && ix >= 0 && ix < W) v = inp[(long)(iy - ibase) * W + ix];
      patch[idx] = v;
    }
    for (int idx = threadIdx.x; idx < 16 * 25; idx += 256) {
      int j = idx / 25, tp = idx - j * 25;
      wt[idx] = wgt[((long)(ocg + j) * Cin + ci) * 25 + tp];
    }
    __syncthreads();
#pragma unroll
    for (int ky = 0; ky < 5; ky++) {
#pragma unroll
      for (int kx = 0; kx < 5; kx++) {
        float iv = patch[(ty * S + ky) * P + tx * S + kx];
        int wof = ky * 5 + kx;
#pragma unroll
        for (int j = 0; j < 16; j++) acc[j] += iv * wt[j * 25 + wof];
      }
    }
    __syncthreads();
  }
  int oy = ty0 + ty, ox = tx0 + tx;
  if (oy < oyend && ox < Wo) {
#pragma unroll
    for (int j = 0; j < 16; j++) {
      float r = fmaxf(acc[j] + bias[ocg + j], 0.f);
      out[(((long)b * Cout + ocg + j) * orows + (oy - obase)) * Wo + ox] = r;
    }
  }
}

// ---------------------------------------------------------------------------
// act4[b,c,h,w] + grid(h,w)@pos_w.T + pos_b -> feat[b, h*32+w, c]
// ---------------------------------------------------------------------------
__global__ __launch_bounds__(256) void posembed_kernel(
    const float* __restrict__ act4, const float* __restrict__ pos_w,
    const float* __restrict__ pos_b, float* __restrict__ feat) {
  int idx = blockIdx.x * 256 + threadIdx.x;  // B*1024*64 = 1048576
  if (idx >= 16 * 1024 * 64) return;
  int c = idx & 63;
  int n = (idx >> 6) & 1023;
  int b = idx >> 16;
  int h = n >> 5, w = n & 31;
  float gh = h * (1.f / 31.f), gw = w * (1.f / 31.f);
  float e = gh * pos_w[c * 4 + 0] + gw * pos_w[c * 4 + 1] +
            (1.f - gh) * pos_w[c * 4 + 2] + (1.f - gw) * pos_w[c * 4 + 3] + pos_b[c];
  feat[idx] = act4[(((long)b * 64 + c) * 32 + h) * 32 + w] + e;
}

// ---------------------------------------------------------------------------
// Per-token (one wave per token): MLP -> LN -> k (l2norm), v, mwi logit
// ---------------------------------------------------------------------------
__global__ __launch_bounds__(64) void token_kernel(
    const float* __restrict__ feat,
    const float* __restrict__ mlp1_w, const float* __restrict__ mlp1_b,
    const float* __restrict__ mlp2_w, const float* __restrict__ mlp2_b,
    const float* __restrict__ lnin_w, const float* __restrict__ lnin_b,
    const float* __restrict__ wk, const float* __restrict__ wv,
    const float* __restrict__ mwi_w, const float* __restrict__ mwi_b,
    float* __restrict__ kn_out, float* __restrict__ v_out, float* __restrict__ lg_out) {
  const int t = blockIdx.x, i = threadIdx.x;
  __shared__ float f[64], h1[64], inp[64];
  f[i] = feat[(long)t * 64 + i];
  __syncthreads();
  float acc = 0.f;
  for (int j = 0; j < 64; j++) acc += f[j] * mlp1_w[i * 64 + j];
  h1[i] = fmaxf(acc + mlp1_b[i], 0.f);
  __syncthreads();
  acc = 0.f;
  for (int j = 0; j < 64; j++) acc += h1[j] * mlp2_w[i * 64 + j];
  float x = acc + mlp2_b[i];
  float m = wsumall(x) * (1.f / 64.f);
  float d0 = x - m;
  float var = wsumall(d0 * d0) * (1.f / 64.f);
  float xin = d0 * rsqrtf(var + LN_EPS) * lnin_w[i] + lnin_b[i];
  inp[i] = xin;
  __syncthreads();
  float kv = 0.f, vv = 0.f;
  for (int j = 0; j < 64; j++) {
    float ij = inp[j];
    kv += ij * wk[i * 64 + j];
    vv += ij * wv[i * 64 + j];
  }
  float ss = wsumall(kv * kv);
  kn_out[(long)t * 64 + i] = kv / fmaxf(sqrtf(ss), 1e-12f);
  v_out[(long)t * 64 + i] = vv;
  float lg = wsumall(xin * mwi_w[i]);
  if (i == 0) lg_out[t] = lg + mwi_b[0];
}

// ---------------------------------------------------------------------------
// logits[b,:] -> log(softmax*8) in place (per-batch block)
// ---------------------------------------------------------------------------
__global__ __launch_bounds__(256) void la_kernel(float* __restrict__ lg) {
  __shared__ float red[256];
  const int b = blockIdx.x, t = threadIdx.x;
  float* p = lg + b * 1024;
  float mx = -1e30f;
  for (int n = t; n < 1024; n += 256) mx = fmaxf(mx, p[n]);
  red[t] = mx;
  __syncthreads();
  for (int o = 128; o; o >>= 1) {
    if (t < o) red[t] = fmaxf(red[t], red[t + o]);
    __syncthreads();
  }
  float M = red[0];
  __syncthreads();
  float s = 0.f;
  for (int n = t; n < 1024; n += 256) s += expf(p[n] - M);
  red[t] = s;
  __syncthreads();
  for (int o = 128; o; o >>= 1) {
    if (t < o) red[t] += red[t + o];
    __syncthreads();
  }
  float lse = M + logf(red[0]);
  __syncthreads();
  for (int n = t; n < 1024; n += 256) p[n] = p[n] - lse + LN8;
}

// ---------------------------------------------------------------------------
// Full slot-attention loop, one block per batch item. 512 threads = 8 waves.
// Wave w owns sinkhorn column s=w. C lives in LDS; gP and u-history in global.
// ---------------------------------------------------------------------------
__global__ __launch_bounds__(512) void sa_kernel(
    const float* __restrict__ kn_g, const float* __restrict__ v_g,
    const float* __restrict__ la_g, const float* __restrict__ noise,
    const float* __restrict__ mu_w, const float* __restrict__ sg_w,
    const float* __restrict__ lnsl_w, const float* __restrict__ lnsl_b,
    const float* __restrict__ mws_w, const float* __restrict__ mws_b,
    const float* __restrict__ wq_w,
    const float* __restrict__ wih, const float* __restrict__ whh,
    const float* __restrict__ bih, const float* __restrict__ bhh,
    const float* __restrict__ lnff_w, const float* __restrict__ lnff_b,
    const float* __restrict__ fc1_w, const float* __restrict__ fc1_b,
    const float* __restrict__ fc2_w, const float* __restrict__ fc2_b,
    float* __restrict__ gws, float* __restrict__ out) {
  const int b = blockIdx.x, tid = threadIdx.x;
  const int wv = tid >> 6, ln = tid & 63;

  __shared__ float sC[8192];                                     // C (then pi)
  __shared__ float sLa[1024], sU[1024], sGu[1024], sRow[1024];
  __shared__ float sVh[48], sV[8], sGv[8], sLb[8], sCol[8], sBm[8];
  __shared__ float sSlots[512], sNorm[512], sQn[512], sUpd[512], sHid[1024];

  const float* kn = kn_g + (long)b * 65536;
  const float* vf = v_g + (long)b * 65536;
  float* gP = gws + (long)b * 13312;
  float* uh = gP + 8192;  // u history: 5*1024

  {  // slots = mu + (|sigma|+eps)*noise
    int dd = tid & 63;
    sSlots[tid] = mu_w[dd] + (fabsf(sg_w[dd]) + SEPS) * noise[(long)b * 512 + tid];
  }
  for (int n = tid; n < 1024; n += 512) sLa[n] = la_g[b * 1024 + n];
  __syncthreads();

  for (int it = 0; it < 3; ++it) {
    // --- slot layernorm (ln_sl), bm logits ---
    {
      float x = sSlots[wv * 64 + ln];
      float m = wsumall(x) * (1.f / 64.f);
      float d0 = x - m;
      float var = wsumall(d0 * d0) * (1.f / 64.f);
      float xn = d0 * rsqrtf(var + LN_EPS) * lnsl_w[ln] + lnsl_b[ln];
      sNorm[wv * 64 + ln] = xn;
      float bmv = wsumall(xn * mws_w[ln]);
      if (ln == 0) sBm[wv] = bmv + mws_b[0];
    }
    __syncthreads();
    if (tid == 0) {  // lb = log(softmax(bm)*8)
      float mx = -1e30f;
      for (int s = 0; s < 8; s++) mx = fmaxf(mx, sBm[s]);
      float ss = 0.f;
      for (int s = 0; s < 8; s++) ss += expf(sBm[s] - mx);
      float lse = mx + logf(ss);
      for (int s = 0; s < 8; s++) sLb[s] = sBm[s] - lse + LN8;
    }
    {  // q = sNorm @ wq.T
      int s = wv, i = ln;
      float acc = 0.f;
      for (int j = 0; j < 64; j++) acc += sNorm[s * 64 + j] * wq_w[i * 64 + j];
      sQn[tid] = acc;
    }
    __syncthreads();
    {  // l2 normalize q per slot
      float qv = sQn[wv * 64 + ln];
      float ss = wsumall(qv * qv);
      sQn[wv * 64 + ln] = qv / fmaxf(sqrtf(ss), 1e-12f);
    }
    if (tid < 8) sV[tid] = 0.f;  // sinkhorn warm start v=0 per SA iteration
    __syncthreads();

    // --- C = 1 - kn . qn ---
    for (int n = tid; n < 1024; n += 512) {
      const float* kr = kn + n * 64;
      float acc[8];
#pragma unroll
      for (int s = 0; s < 8; s++) acc[s] = 0.f;
      for (int j = 0; j < 64; j++) {
        float kvv = kr[j];
#pragma unroll
        for (int s = 0; s < 8; s++) acc[s] += kvv * sQn[s * 64 + j];
      }
#pragma unroll
      for (int s = 0; s < 8; s++) sC[n * 8 + s] = 1.f - acc[s];
    }
    __syncthreads();

    // --- MESH: 4 x (sinkhorn fwd, entropy grad bwd, C += gP) ---
    for (int m = 0; m < 4; m++) {
      if (tid < 8) sVh[tid] = sV[tid];  // v_0
      __syncthreads();
      // forward 5 iterations, save history
      for (int t = 1; t <= 5; t++) {
        for (int n = tid; n < 1024; n += 512) {
          float mx = -1e30f;
#pragma unroll
          for (int s = 0; s < 8; s++) mx = fmaxf(mx, sV[s] - sC[n * 8 + s]);
          float ssum = 0.f;
#pragma unroll
          for (int s = 0; s < 8; s++) ssum += expf(sV[s] - sC[n * 8 + s] - mx);
          float un = sLa[n] - (mx + logf(ssum));
          sU[n] = un;
          uh[(t - 1) * 1024 + n] = un;
        }
        __syncthreads();
        {
          int s = wv;
          float mx = -1e30f;
          for (int n = ln; n < 1024; n += 64) mx = fmaxf(mx, sU[n] - sC[n * 8 + s]);
          mx = wmaxall(mx);
          float ssum = 0.f;
          for (int n = ln; n < 1024; n += 64) ssum += expf(sU[n] - sC[n * 8 + s] - mx);
          ssum = wsumall(ssum);
          if (ln == 0) {
            float vs = sLb[s] - (mx + logf(ssum));
            sV[s] = vs;
            sVh[t * 8 + s] = vs;
          }
        }
        __syncthreads();
      }
      // backward init: gL from entropy; gu = rowsum, gv = colsum
      for (int n = tid; n < 1024; n += 512) {
        float un = sU[n];
        float gul = 0.f;
#pragma unroll
        for (int s = 0; s < 8; s++) {
          float pi = expf(un + sV[s] - sC[n * 8 + s]);
          float gl = -(logf(pi + SEPS) + pi / (pi + SEPS)) * pi * (1.f / 16.f);
          gP[n * 8 + s] = gl;
          gul += gl;
        }
        sGu[n] = gul;
      }
      __syncthreads();
      {  // gv: recompute gl column-wise
        int s = wv;
        float vs = sV[s];
        float acc = 0.f;
        for (int n = ln; n < 1024; n += 64) {
          float pi = expf(sU[n] + vs - sC[n * 8 + s]);
          acc += -(logf(pi + SEPS) + pi / (pi + SEPS)) * pi * (1.f / 16.f);
        }
        acc = wsumall(acc);
        if (ln == 0) sGv[s] = acc;
      }
      __syncthreads();
      // backward through iterations t = 5..1
      for (int t = 5; t >= 1; t--) {
        for (int n = tid; n < 1024; n += 512) sU[n] = uh[(t - 1) * 1024 + n];  // u_t
        __syncthreads();
        {  // column LSE of (u_t - C) for sigma
          int s = wv;
          float mx = -1e30f;
          for (int n = ln; n < 1024; n += 64) mx = fmaxf(mx, sU[n] - sC[n * 8 + s]);
          mx = wmaxall(mx);
          float ssum = 0.f;
          for (int n = ln; n < 1024; n += 64) ssum += expf(sU[n] - sC[n * 8 + s] - mx);
          ssum = wsumall(ssum);
          if (ln == 0) sCol[s] = mx + logf(ssum);
        }
        __syncthreads();
        // sigma row pass: gP -= gv*sigma ; gu -= sum_s gv*sigma
        for (int n = tid; n < 1024; n += 512) {
          float un = sU[n];
          float gul = sGu[n];
#pragma unroll
          for (int s = 0; s < 8; s++) {
            float t2 = sGv[s] * expf(un - sC[n * 8 + s] - sCol[s]);
            gP[n * 8 + s] -= t2;
            gul -= t2;
          }
          sGu[n] = gul;
        }
        __syncthreads();
        // tau row pass: rowLSE of (v_{t-1} - C); gP -= gu*tau
        for (int n = tid; n < 1024; n += 512) {
          float mx = -1e30f;
#pragma unroll
          for (int s = 0; s < 8; s++) mx = fmaxf(mx, sVh[(t - 1) * 8 + s] - sC[n * 8 + s]);
          float ssum = 0.f;
#pragma unroll
          for (int s = 0; s < 8; s++) ssum += expf(sVh[(t - 1) * 8 + s] - sC[n * 8 + s] - mx);
          float lse = mx + logf(ssum);
          sRow[n] = lse;
          float gun = sGu[n];
#pragma unroll
          for (int s = 0; s < 8; s++)
            gP[n * 8 + s] -= gun * expf(sVh[(t - 1) * 8 + s] - sC[n * 8 + s] - lse);
        }
        __syncthreads();
        {  // new gv (grad on v_{t-1}) = -sum_n gu*tau
          int s = wv;
          float vvh = sVh[(t - 1) * 8 + s];
          float acc = 0.f;
          for (int n = ln; n < 1024; n += 64)
            acc += sGu[n] * expf(vvh - sC[n * 8 + s] - sRow[n]);
          acc = wsumall(acc);
          if (ln == 0) sGv[s] = -acc;
        }
        __syncthreads();
        for (int n = tid; n < 1024; n += 512) sGu[n] = 0.f;
        __syncthreads();
      }
      // restore warm start (v5); C += gP (mesh_lr=1, 1/B already in gL)
      if (tid < 8) sV[tid] = sVh[40 + tid];
      __syncthreads();
      for (int i = tid; i < 8192; i += 512) sC[i] += gP[i];
      __syncthreads();
    }

    // --- final sinkhorn (5 iters, warm start v) ---
    for (int t = 0; t < 5; t++) {
      for (int n = tid; n < 1024; n += 512) {
        float mx = -1e30f;
#pragma unroll
        for (int s = 0; s < 8; s++) mx = fmaxf(mx, sV[s] - sC[n * 8 + s]);
        float ssum = 0.f;
#pragma unroll
        for (int s = 0; s < 8; s++) ssum += expf(sV[s] - sC[n * 8 + s] - mx);
        sU[n] = sLa[n] - (mx + logf(ssum));
      }
      __syncthreads();
      {
        int s = wv;
        float mx = -1e30f;
        for (int n = ln; n < 1024; n += 64) mx = fmaxf(mx, sU[n] - sC[n * 8 + s]);
        mx = wmaxall(mx);
        float ssum = 0.f;
        for (int n = ln; n < 1024; n += 64) ssum += expf(sU[n] - sC[n * 8 + s] - mx);
        ssum = wsumall(ssum);
        if (ln == 0) sV[s] = sLb[s] - (mx + logf(ssum));
      }
      __syncthreads();
    }
    // pi in place of C
    for (int n = tid; n < 1024; n += 512) {
      float un = sU[n];
#pragma unroll
      for (int s = 0; s < 8; s++) sC[n * 8 + s] = expf(un + sV[s] - sC[n * 8 + s]);
    }
    __syncthreads();
    if (it == 2) {  // attn[b,s,n] = pi[n,s]  (f32 output)
      for (int o = tid; o < 8192; o += 512) {
        int s = o >> 10, n = o & 1023;
        out[8192 + (long)b * 8192 + o] = sC[n * 8 + s];
      }
    }
    {  // updates[s,d] = sum_n pi[n,s] * v[n,d]
      int s = tid >> 6, dd = tid & 63;
      float acc = 0.f;
      for (int n = 0; n < 1024; n++) acc += sC[n * 8 + s] * vf[n * 64 + dd];
      sUpd[tid] = acc;
    }
    __syncthreads();
    // --- GRU cell ---
    float newslot;
    {
      int s = tid >> 6, i = tid & 63;
      const float* x = &sUpd[s * 64];
      const float* h = &sSlots[s * 64];
      float gir = 0, giz = 0, gin = 0, ghr = 0, ghz = 0, ghn = 0;
      for (int j = 0; j < 64; j++) {
        float xv = x[j], hv = h[j];
        gir += xv * wih[i * 64 + j];
        giz += xv * wih[(64 + i) * 64 + j];
        gin += xv * wih[(128 + i) * 64 + j];
        ghr += hv * whh[i * 64 + j];
        ghz += hv * whh[(64 + i) * 64 + j];
        ghn += hv * whh[(128 + i) * 64 + j];
      }
      gir += bih[i]; giz += bih[64 + i]; gin += bih[128 + i];
      ghr += bhh[i]; ghz += bhh[64 + i]; ghn += bhh[128 + i];
      float r = 1.f / (1.f + expf(-(gir + ghr)));
      float z = 1.f / (1.f + expf(-(giz + ghz)));
      float nn = tanhf(gin + r * ghn);
      newslot = (1.f - z) * nn + z * h[i];
    }
    __syncthreads();
    sSlots[tid] = newslot;
    __syncthreads();
    // --- ln_ff + MLP residual ---
    {
      float x = sSlots[wv * 64 + ln];
      float m = wsumall(x) * (1.f / 64.f);
      float d0 = x - m;
      float var = wsumall(d0 * d0) * (1.f / 64.f);
      sNorm[wv * 64 + ln] = d0 * rsqrtf(var + LN_EPS) * lnff_w[ln] + lnff_b[ln];
    }
    __syncthreads();
    for (int o = tid; o < 1024; o += 512) {
      int s = o >> 7, k2 = o & 127;
      float acc = 0.f;
      for (int j = 0; j < 64; j++) acc += sNorm[s * 64 + j] * fc1_w[k2 * 64 + j];
      sHid[o] = fmaxf(acc + fc1_b[k2], 0.f);
    }
    __syncthreads();
    {
      int s = tid >> 6, i = tid & 63;
      float acc = 0.f;
      for (int j = 0; j < 128; j++) acc += sHid[s * 128 + j] * fc2_w[i * 128 + j];
      newslot = sSlots[tid] + acc + fc2_b[i];
    }
    __syncthreads();
    sSlots[tid] = newslot;
    __syncthreads();
  }
  out[(long)b * 512 + tid] = sSlots[tid];  // f32 output
}

// ---------------------------------------------------------------------------
extern "C" void kernel_launch(void* const* d_in, const int* in_sizes, int n_in,
                              void* d_out, int out_size, void* d_ws, size_t ws_size,
                              hipStream_t stream) {
  (void)n_in; (void)out_size; (void)ws_size;
  char* ws = (char*)d_ws;
  // All-f32 layout, peak 39.4 MiB:
  //   [0,        4.72M)  cvt    converted f32 inputs (persistent)
  //   [4.72M,    5.57M)  gscr   sinkhorn u-history/gP (persistent)
  //   [5.57M,    5.64M)  lgts   (persistent)
  //   [5.64M,   24.51M)  band   conv1 row-band f32; later act3+act4+vf
  //   [24.51M,  41.29M)  act2   f32; later feat+kn
  float* cvt  = (float*)ws;
  float* gscr = (float*)(ws + 4718592ull);
  float* lgts = (float*)(ws + 5570560ull);
  float* band = (float*)(ws + 5636096ull);        // 16*64*36*128 f32 = 18.87 MB
  float* act2 = (float*)(ws + 24510464ull);       // 16*64*64*64 f32 = 16.78 MB
  float* act3 = (float*)(ws + 5636096ull);        // over dead band
  float* act4 = (float*)(ws + 9830400ull);
  float* vf   = (float*)(ws + 14024704ull);       // over dead band tail
  float* feat = (float*)(ws + 24510464ull);       // over dead act2
  float* kn   = (float*)(ws + 28704768ull);
  int*   flag = (int*)(ws + 41287680ull);

  CvtArgs ca;
  long total = 0;
  for (int i = 0; i < 39; i++) { ca.src[i] = d_in[i]; ca.off[i] = total; total += in_sizes[i]; }
  ca.off[39] = total;

  sniff_kernel<<<1, 64, 0, stream>>>((const unsigned int*)d_in[0], flag);
  convert_kernel<<<1024, 256, 0, stream>>>(ca, flag, cvt, total);

#define ARR(i) (cvt + ca.off[i])
  const float* image = ARR(0);
  const float* noise = ARR(1);

  // conv1 -> conv2 fused via 4 row-slices (f32 band buffer reused per slice)
  for (int q = 0; q < 4; q++) {
    int obase = (q == 0) ? 0 : 32 * q - 2;
    int oyend1 = (q == 3) ? 128 : 32 * q + 34;
    conv5x5<1><<<dim3(24, 4, 16), 256, 0, stream>>>(
        image, ARR(2), ARR(3), band, 3, 128, 128, 128, 64, 8,
        obase, oyend1, 0, 128, obase, 36);
    conv5x5<2><<<dim3(4, 4, 16), 256, 0, stream>>>(
        band, ARR(4), ARR(5), act2, 64, 128, 128, 64, 64, 4,
        16 * q, 16 * q + 16, obase, 36, 0, 64);
  }
  conv5x5<2><<<dim3(4, 4, 16), 256, 0, stream>>>(
      act2, ARR(6), ARR(7), act3, 64, 64, 64, 32, 64, 2, 0, 32, 0, 64, 0, 32);
  conv5x5<1><<<dim3(4, 4, 16), 256, 0, stream>>>(
      act3, ARR(8), ARR(9), act4, 64, 32, 32, 32, 64, 2, 0, 32, 0, 32, 0, 32);

  posembed_kernel<<<4096, 256, 0, stream>>>(act4, ARR(10), ARR(11), feat);

  token_kernel<<<16384, 64, 0, stream>>>(feat, ARR(12), ARR(13), ARR(14), ARR(15),
                                         ARR(16), ARR(17), ARR(18), ARR(19), ARR(21), ARR(22),
                                         kn, vf, lgts);

  la_kernel<<<16, 256, 0, stream>>>(lgts);

  sa_kernel<<<16, 512, 0, stream>>>(kn, vf, lgts, noise, ARR(37), ARR(38),
                                    ARR(25), ARR(26), ARR(23), ARR(24), ARR(20),
                                    ARR(27), ARR(28), ARR(29), ARR(30),
                                    ARR(31), ARR(32), ARR(33), ARR(34), ARR(35), ARR(36),
                                    gscr, (float*)d_out);
#undef ARR
}